// Round 1
// 76.406 us; speedup vs baseline: 1.0180x; 1.0180x over previous
//
#include <hip/hip_runtime.h>
#include <float.h>

#define N_SRC 20000
#define N_TAR 20000
#define TPB 512                    // 8 waves/block
#define SPLITS 8                   // source splits (grid.y)
#define PHASES 2                   // staging phases per split (reuse 40 KB LDS)
#define TILES 40                   // 32-source tiles per phase; 8*2*40*32 = 20480 >= 20000
#define TGRP 79                    // target-strip groups (grid.x); 79*8 strips*32 = 20224 >= 20000
#define FBLOCKS ((N_TAR + 255) / 256)

typedef _Float16 half8 __attribute__((ext_vector_type(8)));
typedef float floatx16 __attribute__((ext_vector_type(16)));

// q(t,s) = 0.5||s||^2 - t.s, so 0.5*d2 = 0.5||t||^2 + q.
// One mfma_f32_32x32x16_f16 computes a 32x32 tile of q directly:
//   A row (target t): k0-8 = -t split-f16 cross terms, k9-10 = 1.0
//   B col (source s): k0-8 = s split-f16 terms,        k9-10 = split 0.5||s||^2
// split-f16 (hi/lo) keeps |q error| ~5e-6 (dropped lo*lo only).
// A layout: A[m=lane&31][k=(lane>>5)*8+j]; B[k=(lane>>5)*8+j][n=lane&31];
// C/D: col=lane&31, row=(reg&3)+8*(reg>>2)+4*(lane>>5)  [m74/m101].
//
// R1 changes vs 77.8us baseline:
//  - tiles processed in pairs, folded with fminf(fminf(d0,d1),m) -> v_min3_f32
//    (halves the dominant VALU min-instruction count in the inner loop)
//  - SPLITS 16->8 with 2 staging phases (same 40KB LDS): halves wave count so
//    per-wave fixed costs (A-build, 160-inst butterfly) amortize over 2x tiles;
//    632 blocks fit in one residency round (no tail); part/finalize traffic halves.
__global__ __launch_bounds__(TPB) void nn_mfma(
    const float* __restrict__ src, const float* __restrict__ tar,
    float* __restrict__ part, float* __restrict__ out)
{
    if (blockIdx.x == 0 && blockIdx.y == 0 && threadIdx.x == 0) out[0] = 0.f;

    __shared__ alignas(16) _Float16 lds[TILES * 32 * 16];  // 40 KB

    const int tid  = threadIdx.x;
    const int lane = tid & 63;
    const int col  = lane & 31;
    const int half = (lane >> 5) & 1;
    const int wave = tid >> 6;

    // ---- build A fragment: this wave's 32 targets ----
    const int strip = blockIdx.x * 8 + wave;
    const int t = min(strip * 32 + col, N_TAR - 1);
    const float tx = tar[t * 3 + 0];
    const float ty = tar[t * 3 + 1];
    const float tz = tar[t * 3 + 2];
    const _Float16 txh = (_Float16)tx, tyh = (_Float16)ty, tzh = (_Float16)tz;
    const _Float16 txl = (_Float16)(tx - (float)txh);
    const _Float16 tyl = (_Float16)(ty - (float)tyh);
    const _Float16 tzl = (_Float16)(tz - (float)tzh);
    half8 a;
    if (half == 0)
        a = (half8){-txh, -tyh, -tzh, -txl, -tyl, -tzl, -txh, -tyh};
    else
        a = (half8){-tzh, (_Float16)1.f, (_Float16)1.f, 0, 0, 0, 0, 0};

    floatx16 m;
#pragma unroll
    for (int i = 0; i < 16; ++i) m[i] = FLT_MAX;
    const floatx16 zero = {};  // all-zero accumulator init
    const int foff = col * 16 + half * 8;
    const int sbase0 = blockIdx.y * (PHASES * TILES * 32);

    for (int phase = 0; phase < PHASES; ++phase) {
        if (phase) __syncthreads();  // all waves done reading previous phase's LDS

        // ---- stage B fragments for this phase's 1280 sources ----
        const int pbase = sbase0 + phase * (TILES * 32);
        for (int ls = tid; ls < TILES * 32; ls += TPB) {
            const int s = pbase + ls;
            half8 f0 = {0, 0, 0, 0, 0, 0, 0, 0};
            half8 f1 = {0, 0, 0, 0, 0, 0, 0, 0};
            if (s < N_SRC) {
                const float x = src[s * 3 + 0];
                const float y = src[s * 3 + 1];
                const float z = src[s * 3 + 2];
                const _Float16 xh = (_Float16)x, yh = (_Float16)y, zh = (_Float16)z;
                const _Float16 xl = (_Float16)(x - (float)xh);
                const _Float16 yl = (_Float16)(y - (float)yh);
                const _Float16 zl = (_Float16)(z - (float)zh);
                const float nrm = 0.5f * (x * x + y * y + z * z);
                const _Float16 nh = (_Float16)nrm;
                const _Float16 nl = (_Float16)(nrm - (float)nh);
                f0 = (half8){xh, yh, zh, xh, yh, zh, xl, yl};
                f1 = (half8){zl, nh, nl, 0, 0, 0, 0, 0};
            } else {
                f1 = (half8){0, (_Float16)30000.f, 0, 0, 0, 0, 0, 0}; // never the min
            }
            *(half8*)&lds[ls * 16 + 0] = f0;
            *(half8*)&lds[ls * 16 + 8] = f1;
        }

        __syncthreads();

        // ---- scan tiles in pairs: 2 ds_read_b128 + 2 mfma + 16 v_min3 / 2048 pairs ----
#pragma unroll 2
        for (int tp = 0; tp < TILES; tp += 2) {
            const half8 b0 = *(const half8*)&lds[tp * 512 + foff];
            const half8 b1 = *(const half8*)&lds[(tp + 1) * 512 + foff];
            const floatx16 d0 = __builtin_amdgcn_mfma_f32_32x32x16_f16(a, b0, zero, 0, 0, 0);
            const floatx16 d1 = __builtin_amdgcn_mfma_f32_32x32x16_f16(a, b1, zero, 0, 0, 0);
#pragma unroll
            for (int i = 0; i < 16; ++i)
                m[i] = fminf(fminf(d0[i], d1[i]), m[i]);  // -> v_min3_f32
        }
    }

    // ---- min over the 32 columns (per 32-lane half), then store ----
#pragma unroll
    for (int i = 0; i < 16; ++i) {
        m[i] = fminf(m[i], __shfl_xor(m[i], 1));
        m[i] = fminf(m[i], __shfl_xor(m[i], 2));
        m[i] = fminf(m[i], __shfl_xor(m[i], 4));
        m[i] = fminf(m[i], __shfl_xor(m[i], 8));
        m[i] = fminf(m[i], __shfl_xor(m[i], 16));
    }
    if (col == 0) {
#pragma unroll
        for (int i = 0; i < 16; ++i) {
            const int row = (i & 3) + 8 * (i >> 2) + 4 * half;
            const int tt = min(strip * 32 + row, N_TAR - 1);
            part[blockIdx.y * N_TAR + tt] = m[i];
        }
    }
}

// combine the SPLITS mins per target, add 0.5||t||^2, reduce into out[0]
__global__ __launch_bounds__(256) void nn_finalize(
    const float* __restrict__ tar, const float* __restrict__ part,
    float* __restrict__ out)
{
    const int t = blockIdx.x * 256 + threadIdx.x;
    float contrib = 0.f;
    if (t < N_TAR) {
        float m = FLT_MAX;
#pragma unroll
        for (int c = 0; c < SPLITS; ++c) m = fminf(m, part[c * N_TAR + t]);
        const float tx = tar[t * 3 + 0];
        const float ty = tar[t * 3 + 1];
        const float tz = tar[t * 3 + 2];
        contrib = 0.5f * (tx * tx + ty * ty + tz * tz) + m;
    }
    for (int off = 32; off > 0; off >>= 1)
        contrib += __shfl_down(contrib, off);
    __shared__ float red[4];
    if ((threadIdx.x & 63) == 0) red[threadIdx.x >> 6] = contrib;
    __syncthreads();
    if (threadIdx.x == 0) {
        float s = 0.f;
#pragma unroll
        for (int w = 0; w < 4; ++w) s += red[w];
        atomicAdd(out, s);
    }
}

extern "C" void kernel_launch(void* const* d_in, const int* in_sizes, int n_in,
                              void* d_out, int out_size, void* d_ws, size_t ws_size,
                              hipStream_t stream) {
    const float* src = (const float*)d_in[0];  // [20000,3] fp32
    const float* tar = (const float*)d_in[1];  // [20000,3] fp32
    float* out = (float*)d_out;                // scalar fp32
    float* part = (float*)d_ws;                // SPLITS * N_TAR floats = 640 KB

    dim3 grid1(TGRP, SPLITS);
    nn_mfma<<<grid1, TPB, 0, stream>>>(src, tar, part, out);
    nn_finalize<<<FBLOCKS, 256, 0, stream>>>(tar, part, out);
}